// Round 10
// baseline (301.001 us; speedup 1.0000x reference)
//
#include <hip/hip_runtime.h>

// Problem: B=4,S=2048,D=1024, C=16 chunks, N=2048 codewords, sub=64, K=1.
// R10 = R7 (proven 228.7us: pass1 138 + rest 91) with three surgical cuts:
//  1. med3 top-2 update: s2' = v_med3_f32(s, s1, s2) == exact new second-best
//     -> score update 6->5 VALU ops (VALU is the dominant pipe: 45% busy,
//     pipes serialize per-wave: 31+45=76% summed, 24% idle).
//  2. csq table in LDS (8KB, linear global_load_lds; LDS 72KB still = 2
//     blocks/CU): no global loads left in the nt loop except the tile DMAs.
//  3. prep = fused cbsq+presplit (R5-proven absmax-0): one dispatch + one
//     32MB cb read removed from rest.
// Occupancy-widening abandoned: R2/R8/R9 all show waves/block does not
// convert into residency/speed on this chip.
constexpr int BS    = 8192;
constexpr int CCH   = 16;
constexpr int NCODE = 2048;

using s16x8 = __attribute__((ext_vector_type(8))) short;
using f32x4 = __attribute__((ext_vector_type(4))) float;

// ws layout: float cbsq[32768] @0 (128K) | float cmax @131072 | int bcnt[16] @131076
//   int bwl[16][8192] @131328 (512K) | u64 pbest[16][8192] @655616 (1M, 8-aligned)
//   -> full path needs 2 MB | bf16 cbh @2MB (4M), cbl @6MB (4M) -> presplit needs 10 MB

__device__ __forceinline__ unsigned short bf16_rne(float v) {
    unsigned u = __float_as_uint(v);
    return (unsigned short)((u + 0x7fffu + ((u >> 16) & 1u)) >> 16);
}
__device__ __forceinline__ void split1(float v, unsigned short& h, unsigned short& l) {
    h = bf16_rne(v);
    const float hf = __uint_as_float((unsigned)h << 16);
    l = bf16_rne(v - hf);                 // v-hf exact in fp32
}
__device__ __forceinline__ void split4(float4 v, ushort4& h, ushort4& l) {
    split1(v.x, h.x, l.x); split1(v.y, h.y, l.y);
    split1(v.z, h.z, l.z); split1(v.w, h.w, l.w);
}
// monotonic float->uint encoding (finite): a<b <=> enc(a)<enc(b)
__device__ __forceinline__ unsigned enc_f(float s) {
    unsigned u = __float_as_uint(s);
    return (u & 0x80000000u) ? ~u : (u | 0x80000000u);
}
// median of 3 (finite inputs): with s1<=s2 invariant, med3(s,s1,s2) is the
// exact new second-best of the multiset {s} U top2
__device__ __forceinline__ float med3f(float a, float b, float c) {
    float d;
    asm("v_med3_f32 %0, %1, %2, %3" : "=v"(d) : "v"(a), "v"(b), "v"(c));
    return d;
}

// LDS tile: [row][k 0..63] bf16 (128 B/row); logical 16B chunk ch=k>>3
// stored at phys chunk (ch ^ row) & 7
__device__ __forceinline__ s16x8 ldfrag(const char* buf, int row, int ke) {
    return *(const s16x8*)(buf + row * 128 + ((((ke >> 3) ^ row) & 7) * 16));
}

// direct global->LDS DMA, 16B per lane; LDS dest = wave-uniform base + lane*16
__device__ __forceinline__ void gload16(const void* g, void* l) {
    __builtin_amdgcn_global_load_lds(
        (const __attribute__((address_space(1))) void*)g,
        (__attribute__((address_space(3))) void*)l, 16, 0, 0);
}

// merge (ob1,obi,ob2) into (b1,bi,b2): exact top-2 of union, first-index wins
__device__ __forceinline__ void merge2(float& b1, int& bi, float& b2,
                                       float ob1, int obi, float ob2) {
    b2 = fminf(fminf(b2, ob2), fmaxf(b1, ob1));
    if (ob1 < b1 || (ob1 == b1 && obi < bi)) { b1 = ob1; bi = obi; }
}

// ====== prep: fused cbsq + cmax + (optional) presplit, one dispatch (R5-proven) ======
template<bool SPLIT>
__global__ void prep(const float* __restrict__ cb, float* __restrict__ cbsq,
                     float* __restrict__ cmax,
                     unsigned short* __restrict__ cbh, unsigned short* __restrict__ cbl)
{
    const int g = blockIdx.x * 256 + threadIdx.x;     // float4 id, 0..524287
    const float4 v = ((const float4*)cb)[g];
    if (SPLIT) {
        ushort4 h, l; split4(v, h, l);
        ((ushort4*)cbh)[g] = h;
        ((ushort4*)cbl)[g] = l;
    }
    float s = v.x * v.x + v.y * v.y + v.z * v.z + v.w * v.w;
    s += __shfl_xor(s, 1); s += __shfl_xor(s, 2);
    s += __shfl_xor(s, 4); s += __shfl_xor(s, 8);
    if ((threadIdx.x & 15) == 0) {
        cbsq[g >> 4] = s;
        atomicMax((unsigned*)cmax, __float_as_uint(s));   // s >= 0
    }
}

// =================== FALLBACK: proven R0 fp32 kernel (zero scratch) ===================
__global__ __launch_bounds__(256, 2)
void vq_fp32_fallback(const float* __restrict__ x, const float* __restrict__ cb,
                      float* __restrict__ out)
{
    __shared__ __align__(16) char smraw[65536];
    float4 (*xs)[128] = reinterpret_cast<float4(*)[128]>(smraw);
    float4 (*cs)[128] = reinterpret_cast<float4(*)[128]>(smraw + 32768);
    float  (*rs)[128] = reinterpret_cast<float(*)[128]>(smraw);
    int    (*ri)[128] = reinterpret_cast<int(*)[128]>(smraw + 8192);
    int    *bfin      = reinterpret_cast<int*>(smraw + 16384);

    const int tid = threadIdx.x, tx = tid & 15, ty = tid >> 4;
    const int c = blockIdx.y, mbase = blockIdx.x * 128;
    const float4* xg = (const float4*)x;
    const float4* cg = (const float4*)cb;
    {
        const int k4 = tid & 15, mrow0 = tid >> 4;
#pragma unroll
        for (int i = 0; i < 8; ++i) {
            const int m = i * 16 + mrow0;
            xs[k4][m] = xg[(size_t)(mbase + m) * 256 + c * 16 + k4];
        }
    }
    float best[8]; int bidx[8];
#pragma unroll
    for (int ii = 0; ii < 8; ++ii) { best[ii] = 3.4e38f; bidx[ii] = 0; }
    for (int nt = 0; nt < 16; ++nt) {
        __syncthreads();
        {
            const int k4 = tid & 15, nrow0 = tid >> 4;
#pragma unroll
            for (int i = 0; i < 8; ++i) {
                const int n = i * 16 + nrow0;
                cs[k4][n] = cg[((size_t)c * NCODE + nt * 128 + n) * 16 + k4];
            }
        }
        __syncthreads();
        float acc[8][8], csq[8];
#pragma unroll
        for (int ii = 0; ii < 8; ++ii)
#pragma unroll
            for (int jj = 0; jj < 8; ++jj) acc[ii][jj] = 0.f;
#pragma unroll
        for (int jj = 0; jj < 8; ++jj) csq[jj] = 0.f;
#pragma unroll 2
        for (int k4 = 0; k4 < 16; ++k4) {
            float4 xv[8], cv[8];
#pragma unroll
            for (int ii = 0; ii < 8; ++ii) xv[ii] = xs[k4][tx + 16 * ii];
#pragma unroll
            for (int jj = 0; jj < 8; ++jj) cv[jj] = cs[k4][ty + 16 * jj];
#pragma unroll
            for (int jj = 0; jj < 8; ++jj) {
                csq[jj] = fmaf(cv[jj].x, cv[jj].x, csq[jj]);
                csq[jj] = fmaf(cv[jj].y, cv[jj].y, csq[jj]);
                csq[jj] = fmaf(cv[jj].z, cv[jj].z, csq[jj]);
                csq[jj] = fmaf(cv[jj].w, cv[jj].w, csq[jj]);
            }
#pragma unroll
            for (int ii = 0; ii < 8; ++ii)
#pragma unroll
                for (int jj = 0; jj < 8; ++jj) {
                    acc[ii][jj] = fmaf(xv[ii].x, cv[jj].x, acc[ii][jj]);
                    acc[ii][jj] = fmaf(xv[ii].y, cv[jj].y, acc[ii][jj]);
                    acc[ii][jj] = fmaf(xv[ii].z, cv[jj].z, acc[ii][jj]);
                    acc[ii][jj] = fmaf(xv[ii].w, cv[jj].w, acc[ii][jj]);
                }
        }
#pragma unroll
        for (int jj = 0; jj < 8; ++jj) {
            const int n = nt * 128 + ty + 16 * jj;
#pragma unroll
            for (int ii = 0; ii < 8; ++ii) {
                const float s = fmaf(-2.f, acc[ii][jj], csq[jj]);
                if (s < best[ii]) { best[ii] = s; bidx[ii] = n; }
            }
        }
    }
    __syncthreads();
#pragma unroll
    for (int ii = 0; ii < 8; ++ii) {
        const int m = tx + 16 * ii;
        rs[ty][m] = best[ii]; ri[ty][m] = bidx[ii];
    }
    __syncthreads();
    if (tid < 128) {
        float b = rs[0][tid]; int bi = ri[0][tid];
#pragma unroll
        for (int j = 1; j < 16; ++j) {
            const float s = rs[j][tid]; const int i2 = ri[j][tid];
            if (s < b || (s == b && i2 < bi)) { b = s; bi = i2; }
        }
        bfin[tid] = bi;
    }
    __syncthreads();
    {
        float4* og = (float4*)out;
#pragma unroll
        for (int i = 0; i < 8; ++i) {
            const int flat = i * 256 + tid, m = flat >> 4, q = flat & 15;
            og[(size_t)(mbase + m) * 256 + c * 16 + q] =
                cg[((size_t)c * NCODE + bfin[m]) * 16 + q];
        }
    }
}

// ====== pass 1 (mid-ws fallback, 2-10MB): proven reg-staging path, unchanged ======
template<bool PRESPLIT>
__global__ __launch_bounds__(256, 2)
void pass1(const float* __restrict__ x, const float* __restrict__ cb,
           const unsigned short* __restrict__ cbh, const unsigned short* __restrict__ cbl,
           const float* __restrict__ cbsq, const float* __restrict__ cmax,
           float* __restrict__ out, int* __restrict__ bcnt, int* __restrict__ bwl,
           unsigned long long* __restrict__ pbest)
{
    __shared__ __align__(1024) char sm[65536];
    const int tid  = threadIdx.x;
    const int lane = tid & 63, wv = tid >> 6;
    const int l15  = lane & 15, quad = lane >> 4;
    const int c = blockIdx.y, mbase = blockIdx.x * 128;
    const float4* xg = (const float4*)x;
    const float4* cg = (const float4*)cb;
    const float cmaxs = sqrtf(*cmax);
    const int cwb = (wv & 1) * 64, tkb = (wv >> 1) * 64;

    int tdec[4], ndec[4];
    {
        char* calV = sm;
        char* calO = sm + 16384;
#pragma unroll
        for (int i = 0; i < 8; ++i) {
            const int flat = i * 256 + tid, row = flat >> 4, f4c = flat & 15;
            const int off = row * 128 + ((((f4c >> 1) ^ row) & 7) * 16) + (f4c & 1) * 8;
            const unsigned short hv = bf16_rne((float)(row & 15));
            const unsigned short ho = bf16_rne(1.0f);
            ushort4 v4 = {hv, hv, hv, hv}, o4 = {ho, ho, ho, ho};
            *(ushort4*)(calV + off) = v4;
            *(ushort4*)(calO + off) = o4;
        }
        __syncthreads();
        const int ke = quad * 8;
        const s16x8 aV = ldfrag(calV, cwb + l15, ke);
        const s16x8 aO = ldfrag(calO, cwb + l15, ke);
        const s16x8 bV = ldfrag(calV, tkb + l15, ke);
        const s16x8 bO = ldfrag(calO, tkb + l15, ke);
        f32x4 z; z[0] = z[1] = z[2] = z[3] = 0.f;
        const f32x4 at = __builtin_amdgcn_mfma_f32_16x16x32_bf16(aO, bV, z, 0, 0, 0);
        const f32x4 an = __builtin_amdgcn_mfma_f32_16x16x32_bf16(aV, bO, z, 0, 0, 0);
#pragma unroll
        for (int r = 0; r < 4; ++r) {
            tdec[r] = ((int)(at[r] + 0.5f) >> 5) & 15;
            ndec[r] = ((int)(an[r] + 0.5f) >> 5) & 15;
        }
        __syncthreads();
    }

    char* xs_hi = sm;
    char* xs_lo = sm + 16384;
    {
        float4 xf[8];
#pragma unroll
        for (int i = 0; i < 8; ++i) {
            const int flat = i * 256 + tid;
            xf[i] = xg[(size_t)(mbase + (flat >> 4)) * 256 + c * 16 + (flat & 15)];
        }
#pragma unroll
        for (int i = 0; i < 8; ++i) {
            const int flat = i * 256 + tid, row = flat >> 4, f4c = flat & 15;
            ushort4 h, l; split4(xf[i], h, l);
            const int off = row * 128 + ((((f4c >> 1) ^ row) & 7) * 16) + (f4c & 1) * 8;
            *(ushort4*)(xs_hi + off) = h;
            *(ushort4*)(xs_lo + off) = l;
        }
    }
    __syncthreads();

    s16x8 bhf[4][2], blf[4][2];
#pragma unroll
    for (int jt = 0; jt < 4; ++jt)
#pragma unroll
        for (int ks = 0; ks < 2; ++ks) {
            const int rowt = tkb + jt * 16 + l15;
            const int ke = ks * 32 + quad * 8;
            bhf[jt][ks] = ldfrag(xs_hi, rowt, ke);
            blf[jt][ks] = ldfrag(xs_lo, rowt, ke);
        }

    float4 pf[8];
    uint4  ph[4], pl[4];
    if (PRESPLIT) {
        const uint4* sh = (const uint4*)(cbh + (size_t)c * NCODE * 64);
        const uint4* sl = (const uint4*)(cbl + (size_t)c * NCODE * 64);
#pragma unroll
        for (int i = 0; i < 4; ++i) {
            const int flat = i * 256 + tid;
            ph[i] = sh[flat]; pl[i] = sl[flat];
        }
    } else {
        const float4* src = cg + (size_t)c * NCODE * 16;
#pragma unroll
        for (int i = 0; i < 8; ++i) {
            const int flat = i * 256 + tid;
            pf[i] = src[(size_t)(flat >> 4) * 16 + (flat & 15)];
        }
    }

    float s1[4][4], s2[4][4]; int i1[4][4];
#pragma unroll
    for (int jt = 0; jt < 4; ++jt)
#pragma unroll
        for (int r = 0; r < 4; ++r) { s1[jt][r] = 3.4e38f; s2[jt][r] = 3.4e38f; i1[jt][r] = 0; }

    for (int nt = 0; nt < 16; ++nt) {
        char* chi = (nt & 1) ? sm : sm + 32768;
        char* clo = chi + 16384;
        if (PRESPLIT) {
#pragma unroll
            for (int i = 0; i < 4; ++i) {
                const int flat = i * 256 + tid;
                const int row = flat >> 3, ch = flat & 7;
                const int phys = (ch ^ row) & 7;
                *(uint4*)(chi + row * 128 + phys * 16) = ph[i];
                *(uint4*)(clo + row * 128 + phys * 16) = pl[i];
            }
        } else {
#pragma unroll
            for (int i = 0; i < 8; ++i) {
                const int flat = i * 256 + tid, row = flat >> 4, f4c = flat & 15;
                ushort4 h, l; split4(pf[i], h, l);
                const int off = row * 128 + ((((f4c >> 1) ^ row) & 7) * 16) + (f4c & 1) * 8;
                *(ushort4*)(chi + off) = h;
                *(ushort4*)(clo + off) = l;
            }
        }
        __syncthreads();
        if (nt < 15) {
            if (PRESPLIT) {
                const uint4* sh = (const uint4*)(cbh + ((size_t)c * NCODE + (nt + 1) * 128) * 64);
                const uint4* sl = (const uint4*)(cbl + ((size_t)c * NCODE + (nt + 1) * 128) * 64);
#pragma unroll
                for (int i = 0; i < 4; ++i) {
                    const int flat = i * 256 + tid;
                    ph[i] = sh[flat]; pl[i] = sl[flat];
                }
            } else {
                const float4* src = cg + ((size_t)c * NCODE + (nt + 1) * 128) * 16;
#pragma unroll
                for (int i = 0; i < 8; ++i) {
                    const int flat = i * 256 + tid;
                    pf[i] = src[(size_t)(flat >> 4) * 16 + (flat & 15)];
                }
            }
        }
        const float* cbn = cbsq + c * NCODE + nt * 128;
        float csqv[4][4];
#pragma unroll
        for (int mt = 0; mt < 4; ++mt)
#pragma unroll
            for (int r = 0; r < 4; ++r)
                csqv[mt][r] = cbn[cwb + mt * 16 + ndec[r]];

#pragma unroll
        for (int mt = 0; mt < 4; ++mt) {
            f32x4 accj[4];
#pragma unroll
            for (int jt = 0; jt < 4; ++jt)
#pragma unroll
                for (int e = 0; e < 4; ++e) accj[jt][e] = 0.f;
#pragma unroll
            for (int ks = 0; ks < 2; ++ks) {
                const int ke = ks * 32 + quad * 8;
                const int rowc = cwb + mt * 16 + l15;
                const s16x8 ah = ldfrag(chi, rowc, ke);
                const s16x8 al = ldfrag(clo, rowc, ke);
#pragma unroll
                for (int jt = 0; jt < 4; ++jt) {
                    accj[jt] = __builtin_amdgcn_mfma_f32_16x16x32_bf16(ah, bhf[jt][ks], accj[jt], 0, 0, 0);
                    accj[jt] = __builtin_amdgcn_mfma_f32_16x16x32_bf16(ah, blf[jt][ks], accj[jt], 0, 0, 0);
                    accj[jt] = __builtin_amdgcn_mfma_f32_16x16x32_bf16(al, bhf[jt][ks], accj[jt], 0, 0, 0);
                }
            }
#pragma unroll
            for (int jt = 0; jt < 4; ++jt)
#pragma unroll
                for (int r = 0; r < 4; ++r) {
                    const float s = fmaf(-2.f, accj[jt][r], csqv[mt][r]);
                    const int n = nt * 128 + cwb + mt * 16 + ndec[r];
                    const bool lt = s < s1[jt][r];
                    s2[jt][r] = fminf(s2[jt][r], fmaxf(s, s1[jt][r]));
                    i1[jt][r] = lt ? n : i1[jt][r];
                    s1[jt][r] = fminf(s1[jt][r], s);
                }
        }
    }

    __syncthreads();
    float* s1a = (float*)sm;                // [128][32]
    int*   i1a = (int*)(sm + 16384);
    float* s2a = (float*)(sm + 32768);
    float* sm_part = (float*)(sm + 49152);  // [128][16]
    int*   bfin    = (int*)(sm + 57344);    // [128]
#pragma unroll
    for (int jt = 0; jt < 4; ++jt)
#pragma unroll
        for (int r = 0; r < 4; ++r) {
            const int tok = tkb + jt * 16 + tdec[r];
            const int idx = tok * 32 + (wv & 1) * 16 + ndec[r];
            s1a[idx] = s1[jt][r]; i1a[idx] = i1[jt][r]; s2a[idx] = s2[jt][r];
        }
    {
        const float4* src = xg + (size_t)mbase * 256 + c * 16;
#pragma unroll
        for (int i = 0; i < 8; ++i) {
            const int flat = i * 256 + tid, row = flat >> 4, f4c = flat & 15;
            const float4 v = src[(size_t)row * 256 + f4c];
            sm_part[row * 16 + f4c] = v.x * v.x + v.y * v.y + v.z * v.z + v.w * v.w;
        }
    }
    __syncthreads();
    if (tid < 128) {
        float b1 = 3.4e38f, b2 = 3.4e38f; int bi = 0;
#pragma unroll 4
        for (int e = 0; e < 32; ++e) {
            const float se = s1a[tid * 32 + e];
            const int   ie = i1a[tid * 32 + e];
            const float s2e = s2a[tid * 32 + e];
            if (se < b1 || (se == b1 && ie < bi)) { b2 = fminf(b2, b1); b1 = se; bi = ie; }
            else b2 = fminf(b2, se);
            b2 = fminf(b2, s2e);
        }
        float xsq = 0.f;
#pragma unroll
        for (int q = 0; q < 16; ++q) xsq += sm_part[tid * 16 + q];
        const float eps = 3e-4f + 2e-4f * sqrtf(xsq) * cmaxs;
        bfin[tid] = bi;
        if (b2 - b1 <= 2.f * eps) {
            const int slot = atomicAdd(&bcnt[c], 1);
            bwl[c * 8192 + slot] = mbase + tid;
            pbest[c * 8192 + slot] = ~0ULL;
        }
    }
    __syncthreads();
    {
        float4* og = (float4*)out;
#pragma unroll
        for (int i = 0; i < 8; ++i) {
            const int flat = i * 256 + tid, m = flat >> 4, q = flat & 15;
            og[(size_t)(mbase + m) * 256 + c * 16 + q] =
                cg[((size_t)c * NCODE + bfin[m]) * 16 + q];
        }
    }
}

// ====== pass 1 (presplit >=10MB): R7 structure + csq-in-LDS + med3 update ======
__global__ __launch_bounds__(256, 2)
void pass1_gl(const float* __restrict__ x, const float* __restrict__ cb,
              const unsigned short* __restrict__ cbh, const unsigned short* __restrict__ cbl,
              const float* __restrict__ cbsq, const float* __restrict__ cmax,
              float* __restrict__ out, int* __restrict__ bcnt, int* __restrict__ bwl,
              unsigned long long* __restrict__ pbest)
{
    __shared__ __align__(1024) char sm[73728];   // 64K tiles + 8K csq table
    const int tid  = threadIdx.x;
    const int lane = tid & 63, wv = tid >> 6;
    const int l15  = lane & 15, quad = lane >> 4;
    const int c = blockIdx.y, mbase = blockIdx.x * 128;
    const float4* xg = (const float4*)x;
    const float4* cg = (const float4*)cb;
    const float cmaxs = sqrtf(*cmax);
    const int cwb = (wv & 1) * 64, tkb = (wv >> 1) * 64;

    char* bufA = sm;            // x-stage hi @0, lo @16384; then odd tiles
    char* bufB = sm + 32768;    // tile 0 and even tiles (hi @0, lo @16384)
    float* csq_l = (float*)(sm + 65536);   // fp32 cbsq for this chunk (2048)

    // pre-swizzled per-lane global source offset: LDS off o = chunk + lane*16
    // -> row&7 = lane>>3, phys = lane&7 -> logical ch = (lane&7)^(lane>>3)
    const int lanebyte = ((lane >> 3) << 7) | ((((lane & 7) ^ (lane >> 3)) & 7) << 4);
    const char* srcH = (const char*)cbh + (size_t)c * NCODE * 128;  // 128 B/codeword
    const char* srcL = (const char*)cbl + (size_t)c * NCODE * 128;
    const int wchunk = wv * 4096;   // wave's 4KB slice of a 16KB half-tile

    // issue tile-0 DMA + csq-table DMA (linear) + x loads first
#pragma unroll
    for (int j = 0; j < 4; ++j) {
        const int o = wchunk + j * 1024;
        gload16(srcH + o + lanebyte, bufB + o);
        gload16(srcL + o + lanebyte, bufB + 16384 + o);
    }
    {
        const char* cq = (const char*)(cbsq + (size_t)c * NCODE);
#pragma unroll
        for (int j = 0; j < 2; ++j) {
            const int o = wv * 2048 + j * 1024;      // wave-uniform dest base
            gload16(cq + o + lane * 16, (char*)csq_l + o);
        }
    }
    float4 xf[8];
#pragma unroll
    for (int i = 0; i < 8; ++i) {
        const int flat = i * 256 + tid;
        xf[i] = xg[(size_t)(mbase + (flat >> 4)) * 256 + c * 16 + (flat & 15)];
    }

    // ---- reg-built calibration: decode MFMA D-layout slot -> (t_hat, n_hat)
    int tdec[4], ndec[4];
    {
        const short one = (short)bf16_rne(1.0f);
        const short val = (short)bf16_rne((float)l15);
        s16x8 aV, aO;
#pragma unroll
        for (int e = 0; e < 8; ++e) { aV[e] = val; aO[e] = one; }
        f32x4 z; z[0] = z[1] = z[2] = z[3] = 0.f;
        const f32x4 at = __builtin_amdgcn_mfma_f32_16x16x32_bf16(aO, aV, z, 0, 0, 0);
        const f32x4 an = __builtin_amdgcn_mfma_f32_16x16x32_bf16(aV, aO, z, 0, 0, 0);
#pragma unroll
        for (int r = 0; r < 4; ++r) {
            tdec[r] = ((int)(at[r] + 0.5f) >> 5) & 15;   // D-col (token)
            ndec[r] = ((int)(an[r] + 0.5f) >> 5) & 15;   // D-row (codeword)
        }
    }

    // ---- stage x (split bf16, swizzled) into bufA; |x|^2 partials in regs
    float p8[8];
#pragma unroll
    for (int i = 0; i < 8; ++i) {
        const int flat = i * 256 + tid, row = flat >> 4, f4c = flat & 15;
        ushort4 h, l; split4(xf[i], h, l);
        const int off = row * 128 + ((((f4c >> 1) ^ row) & 7) * 16) + (f4c & 1) * 8;
        *(ushort4*)(bufA + off) = h;
        *(ushort4*)(bufA + 16384 + off) = l;
        p8[i] = xf[i].x * xf[i].x + xf[i].y * xf[i].y + xf[i].z * xf[i].z + xf[i].w * xf[i].w;
    }
    __syncthreads();   // drains vmcnt -> tile0 + csq table resident; xs visible

    // hoist token (B) fragments for the whole nt loop
    s16x8 bhf[4][2], blf[4][2];
#pragma unroll
    for (int jt = 0; jt < 4; ++jt)
#pragma unroll
        for (int ks = 0; ks < 2; ++ks) {
            const int rowt = tkb + jt * 16 + l15;
            const int ke = ks * 32 + quad * 8;
            bhf[jt][ks] = ldfrag(bufA, rowt, ke);
            blf[jt][ks] = ldfrag(bufA + 16384, rowt, ke);
        }
    __syncthreads();   // all hoists done before nt=0 DMAs tile 1 into bufA

    float s1[4][4], s2[4][4]; int i1[4][4];
#pragma unroll
    for (int jt = 0; jt < 4; ++jt)
#pragma unroll
        for (int r = 0; r < 4; ++r) { s1[jt][r] = 3.4e38f; s2[jt][r] = 3.4e38f; i1[jt][r] = 0; }

    for (int nt = 0; nt < 16; ++nt) {
        char* chi = (nt & 1) ? bufA : bufB;
        char* clo = chi + 16384;

        if (nt < 15) {
            char* nh = (nt & 1) ? bufB : bufA;
            const char* th = srcH + (size_t)(nt + 1) * 16384;
            const char* tl = srcL + (size_t)(nt + 1) * 16384;
#pragma unroll
            for (int j = 0; j < 4; ++j) {
                const int o = wchunk + j * 1024;
                gload16(th + o + lanebyte, nh + o);
                gload16(tl + o + lanebyte, nh + 16384 + o);
            }
        }

        // csq from LDS (broadcast ds_read) -- no global loads in loop body
        float csqv[4][4];
#pragma unroll
        for (int mt = 0; mt < 4; ++mt)
#pragma unroll
            for (int r = 0; r < 4; ++r)
                csqv[mt][r] = csq_l[nt * 128 + cwb + mt * 16 + ndec[r]];

#pragma unroll
        for (int mt = 0; mt < 4; ++mt) {
            f32x4 accj[4];
#pragma unroll
            for (int jt = 0; jt < 4; ++jt)
#pragma unroll
                for (int e = 0; e < 4; ++e) accj[jt][e] = 0.f;
#pragma unroll
            for (int ks = 0; ks < 2; ++ks) {
                const int ke = ks * 32 + quad * 8;
                const int rowc = cwb + mt * 16 + l15;
                const s16x8 ah = ldfrag(chi, rowc, ke);
                const s16x8 al = ldfrag(clo, rowc, ke);
#pragma unroll
                for (int jt = 0; jt < 4; ++jt) {
                    accj[jt] = __builtin_amdgcn_mfma_f32_16x16x32_bf16(ah, bhf[jt][ks], accj[jt], 0, 0, 0);
                    accj[jt] = __builtin_amdgcn_mfma_f32_16x16x32_bf16(ah, blf[jt][ks], accj[jt], 0, 0, 0);
                    accj[jt] = __builtin_amdgcn_mfma_f32_16x16x32_bf16(al, bhf[jt][ks], accj[jt], 0, 0, 0);
                }
            }
            // n ascending in (nt,mt) per slot => strict < keeps first-index min
            // med3(s, s1, s2) == exact new second-best (s1<=s2 invariant)
#pragma unroll
            for (int jt = 0; jt < 4; ++jt)
#pragma unroll
                for (int r = 0; r < 4; ++r) {
                    const float s = fmaf(-2.f, accj[jt][r], csqv[mt][r]);
                    const int n = nt * 128 + cwb + mt * 16 + ndec[r];
                    const bool lt = s < s1[jt][r];
                    s2[jt][r] = med3f(s, s1[jt][r], s2[jt][r]);
                    i1[jt][r] = lt ? n : i1[jt][r];
                    s1[jt][r] = fminf(s1[jt][r], s);
                }
        }
        __syncthreads();   // drains vmcnt: tile nt+1 resident; cur readers done
    }

    // ---- epilogue: in-register r-merge + quad shuffle top-2 reduce ----
    float* s1h = (float*)sm;             // [128][2]
    int*   i1h = (int*)  (sm + 1024);    // [128][2]
    float* s2h = (float*)(sm + 2048);    // [128][2]
    float* xsq_l = (float*)(sm + 3072);  // [128]
    int*   bfin  = (int*)  (sm + 3584);  // [128]

#pragma unroll
    for (int jt = 0; jt < 4; ++jt) {
        float b1 = s1[jt][0], b2 = s2[jt][0]; int bi = i1[jt][0];
#pragma unroll
        for (int r = 1; r < 4; ++r)
            merge2(b1, bi, b2, s1[jt][r], i1[jt][r], s2[jt][r]);
        // reduce across the 4 quads (lanes l15, +16, +32, +48: same token)
#pragma unroll
        for (int m = 16; m <= 32; m <<= 1) {
            const float ob1 = __shfl_xor(b1, m);
            const int   obi = __shfl_xor(bi, m);
            const float ob2 = __shfl_xor(b2, m);
            merge2(b1, bi, b2, ob1, obi, ob2);
        }
        if (quad == 0) {
            const int tok = tkb + jt * 16 + tdec[0];
            s1h[tok * 2 + (wv & 1)] = b1;
            i1h[tok * 2 + (wv & 1)] = bi;
            s2h[tok * 2 + (wv & 1)] = b2;
        }
    }
    // xsq: 16 partials per token live in one 16-lane group
#pragma unroll
    for (int i = 0; i < 8; ++i) {
        float v = p8[i];
        v += __shfl_xor(v, 1); v += __shfl_xor(v, 2);
        v += __shfl_xor(v, 4); v += __shfl_xor(v, 8);
        if (l15 == 0) xsq_l[i * 16 + (tid >> 4)] = v;
    }
    __syncthreads();
    if (tid < 128) {
        float b1 = s1h[tid * 2], b2 = s2h[tid * 2]; int bi = i1h[tid * 2];
        merge2(b1, bi, b2, s1h[tid * 2 + 1], i1h[tid * 2 + 1], s2h[tid * 2 + 1]);
        const float xsq = xsq_l[tid];
        const float eps = 3e-4f + 2e-4f * sqrtf(xsq) * cmaxs;
        bfin[tid] = bi;
        if (b2 - b1 <= 2.f * eps) {
            const int slot = atomicAdd(&bcnt[c], 1);   // slot < 8192 structurally
            bwl[c * 8192 + slot] = mbase + tid;
            pbest[c * 8192 + slot] = ~0ULL;            // init merge cell
        }
    }
    __syncthreads();
    {
        float4* og = (float4*)out;
#pragma unroll
        for (int i = 0; i < 8; ++i) {
            const int flat = i * 256 + tid, m = flat >> 4, q = flat & 15;
            og[(size_t)(mbase + m) * 256 + c * 16 + q] =
                cg[((size_t)c * NCODE + bfin[m]) * 16 + q];
        }
    }
}

// ====== pass 2: exact fp32 rescore, PARALLEL over 16 codeword tiles ======
__global__ __launch_bounds__(256, 2)
void pass2_nt(const float* __restrict__ x, const float* __restrict__ cb,
              const int* __restrict__ bcnt, const int* __restrict__ bwl,
              unsigned long long* __restrict__ pbest)
{
    __shared__ __align__(16) char smraw[65536];
    __shared__ int toks[128];
    float4 (*xs)[128] = reinterpret_cast<float4(*)[128]>(smraw);
    float4 (*cs)[128] = reinterpret_cast<float4(*)[128]>(smraw + 32768);
    float  (*rs)[128] = reinterpret_cast<float(*)[128]>(smraw);
    int    (*ri)[128] = reinterpret_cast<int(*)[128]>(smraw + 8192);

    const int c = blockIdx.y, ntb = blockIdx.x;
    const int cnt = bcnt[c];
    if (cnt == 0) return;
    const int tid = threadIdx.x, tx = tid & 15, ty = tid >> 4;
    const float4* xg = (const float4*)x;
    const float4* cg = (const float4*)cb;

    {
        const int k4 = tid & 15, nrow0 = tid >> 4;
#pragma unroll
        for (int i = 0; i < 8; ++i) {
            const int n = i * 16 + nrow0;
            cs[k4][n] = cg[((size_t)c * NCODE + ntb * 128 + n) * 16 + k4];
        }
    }

    for (int g0 = 0; g0 < cnt; g0 += 128) {
        __syncthreads();
        if (tid < 128) {
            const int e = g0 + tid;
            toks[tid] = bwl[c * 8192 + (e < cnt ? e : g0)];
        }
        __syncthreads();
        {
            const int k4 = tid & 15, mrow0 = tid >> 4;
#pragma unroll
            for (int i = 0; i < 8; ++i) {
                const int m = i * 16 + mrow0;
                xs[k4][m] = xg[(size_t)toks[m] * 256 + c * 16 + k4];
            }
        }
        __syncthreads();
        float acc[8][8], csq[8];
#pragma unroll
        for (int ii = 0; ii < 8; ++ii)
#pragma unroll
            for (int jj = 0; jj < 8; ++jj) acc[ii][jj] = 0.f;
#pragma unroll
        for (int jj = 0; jj < 8; ++jj) csq[jj] = 0.f;
#pragma unroll 2
        for (int k4 = 0; k4 < 16; ++k4) {
            float4 xv[8], cv[8];
#pragma unroll
            for (int ii = 0; ii < 8; ++ii) xv[ii] = xs[k4][tx + 16 * ii];
#pragma unroll
            for (int jj = 0; jj < 8; ++jj) cv[jj] = cs[k4][ty + 16 * jj];
#pragma unroll
            for (int jj = 0; jj < 8; ++jj) {
                csq[jj] = fmaf(cv[jj].x, cv[jj].x, csq[jj]);
                csq[jj] = fmaf(cv[jj].y, cv[jj].y, csq[jj]);
                csq[jj] = fmaf(cv[jj].z, cv[jj].z, csq[jj]);
                csq[jj] = fmaf(cv[jj].w, cv[jj].w, csq[jj]);
            }
#pragma unroll
            for (int ii = 0; ii < 8; ++ii)
#pragma unroll
                for (int jj = 0; jj < 8; ++jj) {
                    acc[ii][jj] = fmaf(xv[ii].x, cv[jj].x, acc[ii][jj]);
                    acc[ii][jj] = fmaf(xv[ii].y, cv[jj].y, acc[ii][jj]);
                    acc[ii][jj] = fmaf(xv[ii].z, cv[jj].z, acc[ii][jj]);
                    acc[ii][jj] = fmaf(xv[ii].w, cv[jj].w, acc[ii][jj]);
                }
        }
        float best[8]; int bidx[8];
#pragma unroll
        for (int ii = 0; ii < 8; ++ii) { best[ii] = 3.4e38f; bidx[ii] = 0; }
#pragma unroll
        for (int jj = 0; jj < 8; ++jj) {
            const int n = ntb * 128 + ty + 16 * jj;
#pragma unroll
            for (int ii = 0; ii < 8; ++ii) {
                const float s = fmaf(-2.f, acc[ii][jj], csq[jj]);
                if (s < best[ii]) { best[ii] = s; bidx[ii] = n; }
            }
        }
        __syncthreads();
#pragma unroll
        for (int ii = 0; ii < 8; ++ii) {
            const int m = tx + 16 * ii;
            rs[ty][m] = best[ii]; ri[ty][m] = bidx[ii];
        }
        __syncthreads();
        if (tid < 128 && g0 + tid < cnt) {
            float b = rs[0][tid]; int bi = ri[0][tid];
#pragma unroll
            for (int j = 1; j < 16; ++j) {
                const float s = rs[j][tid]; const int i2 = ri[j][tid];
                if (s < b || (s == b && i2 < bi)) { b = s; bi = i2; }
            }
            const unsigned long long pk =
                ((unsigned long long)enc_f(b) << 32) | (unsigned)bi;
            atomicMin(&pbest[c * 8192 + g0 + tid], pk);
        }
    }
}

// ====== pass 3: gather winners for flagged tokens ======
__global__ void pass3(const float* __restrict__ cb, float* __restrict__ out,
                      const int* __restrict__ bcnt, const int* __restrict__ bwl,
                      const unsigned long long* __restrict__ pbest)
{
    const int c = blockIdx.y;
    const int cnt = bcnt[c];
    const float4* cg = (const float4*)cb;
    float4* og = (float4*)out;
    const int q = threadIdx.x & 15;
    for (int e = blockIdx.x * 16 + (threadIdx.x >> 4); e < cnt; e += 64 * 16) {
        const int tok = bwl[c * 8192 + e];
        const unsigned n = (unsigned)(pbest[c * 8192 + e] & 0xFFFFFFFFull);
        og[(size_t)tok * 256 + c * 16 + q] = cg[((size_t)c * NCODE + n) * 16 + q];
    }
}

extern "C" void kernel_launch(void* const* d_in, const int* in_sizes, int n_in,
                              void* d_out, int out_size, void* d_ws, size_t ws_size,
                              hipStream_t stream)
{
    const float* x  = (const float*)d_in[0];
    const float* cb = (const float*)d_in[1];
    float* out      = (float*)d_out;

    if (ws_size < (size_t)(2u << 20)) {
        dim3 grid(BS / 128, CCH);
        vq_fp32_fallback<<<grid, 256, 0, stream>>>(x, cb, out);
        return;
    }
    char* ws = (char*)d_ws;
    float* cbsq = (float*)ws;
    float* cmax = (float*)(ws + 131072);
    int*   bcnt = (int*)(ws + 131076);
    int*   bwl  = (int*)(ws + 131328);
    unsigned long long* pbest = (unsigned long long*)(ws + 655616);
    unsigned short* cbh = (unsigned short*)(ws + (2u << 20));
    unsigned short* cbl = (unsigned short*)(ws + (6u << 20));

    // cmax (4B) + bcnt[16] (64B) are contiguous: one capture-safe memset
    hipMemsetAsync(ws + 131072, 0, 68, stream);
    if (ws_size >= (size_t)(10u << 20)) {
        prep<true><<<2048, 256, 0, stream>>>(cb, cbsq, cmax, cbh, cbl);
        pass1_gl<<<dim3(BS / 128, CCH), 256, 0, stream>>>(x, cb, cbh, cbl, cbsq, cmax, out, bcnt, bwl, pbest);
    } else {
        prep<false><<<2048, 256, 0, stream>>>(cb, cbsq, cmax, nullptr, nullptr);
        pass1<false><<<dim3(BS / 128, CCH), 256, 0, stream>>>(x, cb, nullptr, nullptr, cbsq, cmax, out, bcnt, bwl, pbest);
    }
    pass2_nt<<<dim3(16, CCH), 256, 0, stream>>>(x, cb, bcnt, bwl, pbest);
    pass3<<<dim3(64, CCH), 256, 0, stream>>>(cb, out, bcnt, bwl, pbest);
}

// Round 11
// 219.599 us; speedup vs baseline: 1.3707x; 1.3707x over previous
//
#include <hip/hip_runtime.h>

// Problem: B=4,S=2048,D=1024, C=16 chunks, N=2048 codewords, sub=64, K=1.
// R11 = proven-best composition, zero new code paths:
//  - pass1_gl: R10's exact kernel (130us, absmax 0): R7 structure + med3
//    top-2 update + csq table in LDS (72KB, still 2 blocks/CU).
//  - rest: R7's exact four kernels (cbsq_kernel/presplit_cb/pass2_nt/pass3,
//    ~91us). Ledger across R5/R6/R8/R10 shows the fused `prep` costs
//    ~+80us of rest every time it appears -> abandoned (like widening).
constexpr int BS    = 8192;
constexpr int CCH   = 16;
constexpr int NCODE = 2048;

using s16x8 = __attribute__((ext_vector_type(8))) short;
using f32x4 = __attribute__((ext_vector_type(4))) float;

// ws layout: float cbsq[32768] @0 (128K) | float cmax @131072 | int bcnt[16] @131076
//   int bwl[16][8192] @131328 (512K) | u64 pbest[16][8192] @655616 (1M, 8-aligned)
//   -> full path needs 2 MB | bf16 cbh @2MB (4M), cbl @6MB (4M) -> presplit needs 10 MB

__device__ __forceinline__ unsigned short bf16_rne(float v) {
    unsigned u = __float_as_uint(v);
    return (unsigned short)((u + 0x7fffu + ((u >> 16) & 1u)) >> 16);
}
__device__ __forceinline__ void split1(float v, unsigned short& h, unsigned short& l) {
    h = bf16_rne(v);
    const float hf = __uint_as_float((unsigned)h << 16);
    l = bf16_rne(v - hf);                 // v-hf exact in fp32
}
__device__ __forceinline__ void split4(float4 v, ushort4& h, ushort4& l) {
    split1(v.x, h.x, l.x); split1(v.y, h.y, l.y);
    split1(v.z, h.z, l.z); split1(v.w, h.w, l.w);
}
// monotonic float->uint encoding (finite): a<b <=> enc(a)<enc(b)
__device__ __forceinline__ unsigned enc_f(float s) {
    unsigned u = __float_as_uint(s);
    return (u & 0x80000000u) ? ~u : (u | 0x80000000u);
}
// median of 3 (finite inputs): with s1<=s2 invariant, med3(s,s1,s2) is the
// exact new second-best of the multiset {s} U top2
__device__ __forceinline__ float med3f(float a, float b, float c) {
    float d;
    asm("v_med3_f32 %0, %1, %2, %3" : "=v"(d) : "v"(a), "v"(b), "v"(c));
    return d;
}

// LDS tile: [row][k 0..63] bf16 (128 B/row); logical 16B chunk ch=k>>3
// stored at phys chunk (ch ^ row) & 7
__device__ __forceinline__ s16x8 ldfrag(const char* buf, int row, int ke) {
    return *(const s16x8*)(buf + row * 128 + ((((ke >> 3) ^ row) & 7) * 16));
}

// direct global->LDS DMA, 16B per lane; LDS dest = wave-uniform base + lane*16
__device__ __forceinline__ void gload16(const void* g, void* l) {
    __builtin_amdgcn_global_load_lds(
        (const __attribute__((address_space(1))) void*)g,
        (__attribute__((address_space(3))) void*)l, 16, 0, 0);
}

// merge (ob1,obi,ob2) into (b1,bi,b2): exact top-2 of union, first-index wins
__device__ __forceinline__ void merge2(float& b1, int& bi, float& b2,
                                       float ob1, int obi, float ob2) {
    b2 = fminf(fminf(b2, ob2), fmaxf(b1, ob1));
    if (ob1 < b1 || (ob1 == b1 && obi < bi)) { b1 = ob1; bi = obi; }
}

__global__ void cbsq_kernel(const float* __restrict__ cb, float* __restrict__ cbsq,
                            float* __restrict__ cmax)
{
    const int g = blockIdx.x * 256 + threadIdx.x;
    const float4* cg = (const float4*)cb;
    float s = 0.f;
#pragma unroll
    for (int q = 0; q < 16; ++q) {
        float4 v = cg[(size_t)g * 16 + q];
        s = fmaf(v.x, v.x, s); s = fmaf(v.y, v.y, s);
        s = fmaf(v.z, v.z, s); s = fmaf(v.w, v.w, s);
    }
    cbsq[g] = s;
    atomicMax((unsigned*)cmax, __float_as_uint(s));   // s >= 0
}

__global__ void presplit_cb(const float* __restrict__ cb,
                            unsigned short* __restrict__ cbh,
                            unsigned short* __restrict__ cbl)
{
    const int g = blockIdx.x * 256 + threadIdx.x;     // 0..524287 float4s
    const float4 v = ((const float4*)cb)[g];
    ushort4 h, l; split4(v, h, l);
    ((ushort4*)cbh)[g] = h;
    ((ushort4*)cbl)[g] = l;
}

// =================== FALLBACK: proven R0 fp32 kernel (zero scratch) ===================
__global__ __launch_bounds__(256, 2)
void vq_fp32_fallback(const float* __restrict__ x, const float* __restrict__ cb,
                      float* __restrict__ out)
{
    __shared__ __align__(16) char smraw[65536];
    float4 (*xs)[128] = reinterpret_cast<float4(*)[128]>(smraw);
    float4 (*cs)[128] = reinterpret_cast<float4(*)[128]>(smraw + 32768);
    float  (*rs)[128] = reinterpret_cast<float(*)[128]>(smraw);
    int    (*ri)[128] = reinterpret_cast<int(*)[128]>(smraw + 8192);
    int    *bfin      = reinterpret_cast<int*>(smraw + 16384);

    const int tid = threadIdx.x, tx = tid & 15, ty = tid >> 4;
    const int c = blockIdx.y, mbase = blockIdx.x * 128;
    const float4* xg = (const float4*)x;
    const float4* cg = (const float4*)cb;
    {
        const int k4 = tid & 15, mrow0 = tid >> 4;
#pragma unroll
        for (int i = 0; i < 8; ++i) {
            const int m = i * 16 + mrow0;
            xs[k4][m] = xg[(size_t)(mbase + m) * 256 + c * 16 + k4];
        }
    }
    float best[8]; int bidx[8];
#pragma unroll
    for (int ii = 0; ii < 8; ++ii) { best[ii] = 3.4e38f; bidx[ii] = 0; }
    for (int nt = 0; nt < 16; ++nt) {
        __syncthreads();
        {
            const int k4 = tid & 15, nrow0 = tid >> 4;
#pragma unroll
            for (int i = 0; i < 8; ++i) {
                const int n = i * 16 + nrow0;
                cs[k4][n] = cg[((size_t)c * NCODE + nt * 128 + n) * 16 + k4];
            }
        }
        __syncthreads();
        float acc[8][8], csq[8];
#pragma unroll
        for (int ii = 0; ii < 8; ++ii)
#pragma unroll
            for (int jj = 0; jj < 8; ++jj) acc[ii][jj] = 0.f;
#pragma unroll
        for (int jj = 0; jj < 8; ++jj) csq[jj] = 0.f;
#pragma unroll 2
        for (int k4 = 0; k4 < 16; ++k4) {
            float4 xv[8], cv[8];
#pragma unroll
            for (int ii = 0; ii < 8; ++ii) xv[ii] = xs[k4][tx + 16 * ii];
#pragma unroll
            for (int jj = 0; jj < 8; ++jj) cv[jj] = cs[k4][ty + 16 * jj];
#pragma unroll
            for (int jj = 0; jj < 8; ++jj) {
                csq[jj] = fmaf(cv[jj].x, cv[jj].x, csq[jj]);
                csq[jj] = fmaf(cv[jj].y, cv[jj].y, csq[jj]);
                csq[jj] = fmaf(cv[jj].z, cv[jj].z, csq[jj]);
                csq[jj] = fmaf(cv[jj].w, cv[jj].w, csq[jj]);
            }
#pragma unroll
            for (int ii = 0; ii < 8; ++ii)
#pragma unroll
                for (int jj = 0; jj < 8; ++jj) {
                    acc[ii][jj] = fmaf(xv[ii].x, cv[jj].x, acc[ii][jj]);
                    acc[ii][jj] = fmaf(xv[ii].y, cv[jj].y, acc[ii][jj]);
                    acc[ii][jj] = fmaf(xv[ii].z, cv[jj].z, acc[ii][jj]);
                    acc[ii][jj] = fmaf(xv[ii].w, cv[jj].w, acc[ii][jj]);
                }
        }
#pragma unroll
        for (int jj = 0; jj < 8; ++jj) {
            const int n = nt * 128 + ty + 16 * jj;
#pragma unroll
            for (int ii = 0; ii < 8; ++ii) {
                const float s = fmaf(-2.f, acc[ii][jj], csq[jj]);
                if (s < best[ii]) { best[ii] = s; bidx[ii] = n; }
            }
        }
    }
    __syncthreads();
#pragma unroll
    for (int ii = 0; ii < 8; ++ii) {
        const int m = tx + 16 * ii;
        rs[ty][m] = best[ii]; ri[ty][m] = bidx[ii];
    }
    __syncthreads();
    if (tid < 128) {
        float b = rs[0][tid]; int bi = ri[0][tid];
#pragma unroll
        for (int j = 1; j < 16; ++j) {
            const float s = rs[j][tid]; const int i2 = ri[j][tid];
            if (s < b || (s == b && i2 < bi)) { b = s; bi = i2; }
        }
        bfin[tid] = bi;
    }
    __syncthreads();
    {
        float4* og = (float4*)out;
#pragma unroll
        for (int i = 0; i < 8; ++i) {
            const int flat = i * 256 + tid, m = flat >> 4, q = flat & 15;
            og[(size_t)(mbase + m) * 256 + c * 16 + q] =
                cg[((size_t)c * NCODE + bfin[m]) * 16 + q];
        }
    }
}

// ====== pass 1 (mid-ws fallback, 2-10MB): proven reg-staging path, unchanged ======
template<bool PRESPLIT>
__global__ __launch_bounds__(256, 2)
void pass1(const float* __restrict__ x, const float* __restrict__ cb,
           const unsigned short* __restrict__ cbh, const unsigned short* __restrict__ cbl,
           const float* __restrict__ cbsq, const float* __restrict__ cmax,
           float* __restrict__ out, int* __restrict__ bcnt, int* __restrict__ bwl,
           unsigned long long* __restrict__ pbest)
{
    __shared__ __align__(1024) char sm[65536];
    const int tid  = threadIdx.x;
    const int lane = tid & 63, wv = tid >> 6;
    const int l15  = lane & 15, quad = lane >> 4;
    const int c = blockIdx.y, mbase = blockIdx.x * 128;
    const float4* xg = (const float4*)x;
    const float4* cg = (const float4*)cb;
    const float cmaxs = sqrtf(*cmax);
    const int cwb = (wv & 1) * 64, tkb = (wv >> 1) * 64;

    int tdec[4], ndec[4];
    {
        char* calV = sm;
        char* calO = sm + 16384;
#pragma unroll
        for (int i = 0; i < 8; ++i) {
            const int flat = i * 256 + tid, row = flat >> 4, f4c = flat & 15;
            const int off = row * 128 + ((((f4c >> 1) ^ row) & 7) * 16) + (f4c & 1) * 8;
            const unsigned short hv = bf16_rne((float)(row & 15));
            const unsigned short ho = bf16_rne(1.0f);
            ushort4 v4 = {hv, hv, hv, hv}, o4 = {ho, ho, ho, ho};
            *(ushort4*)(calV + off) = v4;
            *(ushort4*)(calO + off) = o4;
        }
        __syncthreads();
        const int ke = quad * 8;
        const s16x8 aV = ldfrag(calV, cwb + l15, ke);
        const s16x8 aO = ldfrag(calO, cwb + l15, ke);
        const s16x8 bV = ldfrag(calV, tkb + l15, ke);
        const s16x8 bO = ldfrag(calO, tkb + l15, ke);
        f32x4 z; z[0] = z[1] = z[2] = z[3] = 0.f;
        const f32x4 at = __builtin_amdgcn_mfma_f32_16x16x32_bf16(aO, bV, z, 0, 0, 0);
        const f32x4 an = __builtin_amdgcn_mfma_f32_16x16x32_bf16(aV, bO, z, 0, 0, 0);
#pragma unroll
        for (int r = 0; r < 4; ++r) {
            tdec[r] = ((int)(at[r] + 0.5f) >> 5) & 15;
            ndec[r] = ((int)(an[r] + 0.5f) >> 5) & 15;
        }
        __syncthreads();
    }

    char* xs_hi = sm;
    char* xs_lo = sm + 16384;
    {
        float4 xf[8];
#pragma unroll
        for (int i = 0; i < 8; ++i) {
            const int flat = i * 256 + tid;
            xf[i] = xg[(size_t)(mbase + (flat >> 4)) * 256 + c * 16 + (flat & 15)];
        }
#pragma unroll
        for (int i = 0; i < 8; ++i) {
            const int flat = i * 256 + tid, row = flat >> 4, f4c = flat & 15;
            ushort4 h, l; split4(xf[i], h, l);
            const int off = row * 128 + ((((f4c >> 1) ^ row) & 7) * 16) + (f4c & 1) * 8;
            *(ushort4*)(xs_hi + off) = h;
            *(ushort4*)(xs_lo + off) = l;
        }
    }
    __syncthreads();

    s16x8 bhf[4][2], blf[4][2];
#pragma unroll
    for (int jt = 0; jt < 4; ++jt)
#pragma unroll
        for (int ks = 0; ks < 2; ++ks) {
            const int rowt = tkb + jt * 16 + l15;
            const int ke = ks * 32 + quad * 8;
            bhf[jt][ks] = ldfrag(xs_hi, rowt, ke);
            blf[jt][ks] = ldfrag(xs_lo, rowt, ke);
        }

    float4 pf[8];
    uint4  ph[4], pl[4];
    if (PRESPLIT) {
        const uint4* sh = (const uint4*)(cbh + (size_t)c * NCODE * 64);
        const uint4* sl = (const uint4*)(cbl + (size_t)c * NCODE * 64);
#pragma unroll
        for (int i = 0; i < 4; ++i) {
            const int flat = i * 256 + tid;
            ph[i] = sh[flat]; pl[i] = sl[flat];
        }
    } else {
        const float4* src = cg + (size_t)c * NCODE * 16;
#pragma unroll
        for (int i = 0; i < 8; ++i) {
            const int flat = i * 256 + tid;
            pf[i] = src[(size_t)(flat >> 4) * 16 + (flat & 15)];
        }
    }

    float s1[4][4], s2[4][4]; int i1[4][4];
#pragma unroll
    for (int jt = 0; jt < 4; ++jt)
#pragma unroll
        for (int r = 0; r < 4; ++r) { s1[jt][r] = 3.4e38f; s2[jt][r] = 3.4e38f; i1[jt][r] = 0; }

    for (int nt = 0; nt < 16; ++nt) {
        char* chi = (nt & 1) ? sm : sm + 32768;
        char* clo = chi + 16384;
        if (PRESPLIT) {
#pragma unroll
            for (int i = 0; i < 4; ++i) {
                const int flat = i * 256 + tid;
                const int row = flat >> 3, ch = flat & 7;
                const int phys = (ch ^ row) & 7;
                *(uint4*)(chi + row * 128 + phys * 16) = ph[i];
                *(uint4*)(clo + row * 128 + phys * 16) = pl[i];
            }
        } else {
#pragma unroll
            for (int i = 0; i < 8; ++i) {
                const int flat = i * 256 + tid, row = flat >> 4, f4c = flat & 15;
                ushort4 h, l; split4(pf[i], h, l);
                const int off = row * 128 + ((((f4c >> 1) ^ row) & 7) * 16) + (f4c & 1) * 8;
                *(ushort4*)(chi + off) = h;
                *(ushort4*)(clo + off) = l;
            }
        }
        __syncthreads();
        if (nt < 15) {
            if (PRESPLIT) {
                const uint4* sh = (const uint4*)(cbh + ((size_t)c * NCODE + (nt + 1) * 128) * 64);
                const uint4* sl = (const uint4*)(cbl + ((size_t)c * NCODE + (nt + 1) * 128) * 64);
#pragma unroll
                for (int i = 0; i < 4; ++i) {
                    const int flat = i * 256 + tid;
                    ph[i] = sh[flat]; pl[i] = sl[flat];
                }
            } else {
                const float4* src = cg + ((size_t)c * NCODE + (nt + 1) * 128) * 16;
#pragma unroll
                for (int i = 0; i < 8; ++i) {
                    const int flat = i * 256 + tid;
                    pf[i] = src[(size_t)(flat >> 4) * 16 + (flat & 15)];
                }
            }
        }
        const float* cbn = cbsq + c * NCODE + nt * 128;
        float csqv[4][4];
#pragma unroll
        for (int mt = 0; mt < 4; ++mt)
#pragma unroll
            for (int r = 0; r < 4; ++r)
                csqv[mt][r] = cbn[cwb + mt * 16 + ndec[r]];

#pragma unroll
        for (int mt = 0; mt < 4; ++mt) {
            f32x4 accj[4];
#pragma unroll
            for (int jt = 0; jt < 4; ++jt)
#pragma unroll
                for (int e = 0; e < 4; ++e) accj[jt][e] = 0.f;
#pragma unroll
            for (int ks = 0; ks < 2; ++ks) {
                const int ke = ks * 32 + quad * 8;
                const int rowc = cwb + mt * 16 + l15;
                const s16x8 ah = ldfrag(chi, rowc, ke);
                const s16x8 al = ldfrag(clo, rowc, ke);
#pragma unroll
                for (int jt = 0; jt < 4; ++jt) {
                    accj[jt] = __builtin_amdgcn_mfma_f32_16x16x32_bf16(ah, bhf[jt][ks], accj[jt], 0, 0, 0);
                    accj[jt] = __builtin_amdgcn_mfma_f32_16x16x32_bf16(ah, blf[jt][ks], accj[jt], 0, 0, 0);
                    accj[jt] = __builtin_amdgcn_mfma_f32_16x16x32_bf16(al, bhf[jt][ks], accj[jt], 0, 0, 0);
                }
            }
#pragma unroll
            for (int jt = 0; jt < 4; ++jt)
#pragma unroll
                for (int r = 0; r < 4; ++r) {
                    const float s = fmaf(-2.f, accj[jt][r], csqv[mt][r]);
                    const int n = nt * 128 + cwb + mt * 16 + ndec[r];
                    const bool lt = s < s1[jt][r];
                    s2[jt][r] = fminf(s2[jt][r], fmaxf(s, s1[jt][r]));
                    i1[jt][r] = lt ? n : i1[jt][r];
                    s1[jt][r] = fminf(s1[jt][r], s);
                }
        }
    }

    __syncthreads();
    float* s1a = (float*)sm;                // [128][32]
    int*   i1a = (int*)(sm + 16384);
    float* s2a = (float*)(sm + 32768);
    float* sm_part = (float*)(sm + 49152);  // [128][16]
    int*   bfin    = (int*)(sm + 57344);    // [128]
#pragma unroll
    for (int jt = 0; jt < 4; ++jt)
#pragma unroll
        for (int r = 0; r < 4; ++r) {
            const int tok = tkb + jt * 16 + tdec[r];
            const int idx = tok * 32 + (wv & 1) * 16 + ndec[r];
            s1a[idx] = s1[jt][r]; i1a[idx] = i1[jt][r]; s2a[idx] = s2[jt][r];
        }
    {
        const float4* src = xg + (size_t)mbase * 256 + c * 16;
#pragma unroll
        for (int i = 0; i < 8; ++i) {
            const int flat = i * 256 + tid, row = flat >> 4, f4c = flat & 15;
            const float4 v = src[(size_t)row * 256 + f4c];
            sm_part[row * 16 + f4c] = v.x * v.x + v.y * v.y + v.z * v.z + v.w * v.w;
        }
    }
    __syncthreads();
    if (tid < 128) {
        float b1 = 3.4e38f, b2 = 3.4e38f; int bi = 0;
#pragma unroll 4
        for (int e = 0; e < 32; ++e) {
            const float se = s1a[tid * 32 + e];
            const int   ie = i1a[tid * 32 + e];
            const float s2e = s2a[tid * 32 + e];
            if (se < b1 || (se == b1 && ie < bi)) { b2 = fminf(b2, b1); b1 = se; bi = ie; }
            else b2 = fminf(b2, se);
            b2 = fminf(b2, s2e);
        }
        float xsq = 0.f;
#pragma unroll
        for (int q = 0; q < 16; ++q) xsq += sm_part[tid * 16 + q];
        const float eps = 3e-4f + 2e-4f * sqrtf(xsq) * cmaxs;
        bfin[tid] = bi;
        if (b2 - b1 <= 2.f * eps) {
            const int slot = atomicAdd(&bcnt[c], 1);
            bwl[c * 8192 + slot] = mbase + tid;
            pbest[c * 8192 + slot] = ~0ULL;
        }
    }
    __syncthreads();
    {
        float4* og = (float4*)out;
#pragma unroll
        for (int i = 0; i < 8; ++i) {
            const int flat = i * 256 + tid, m = flat >> 4, q = flat & 15;
            og[(size_t)(mbase + m) * 256 + c * 16 + q] =
                cg[((size_t)c * NCODE + bfin[m]) * 16 + q];
        }
    }
}

// ====== pass 1 (presplit >=10MB): R10's exact kernel (proven 130us) ======
__global__ __launch_bounds__(256, 2)
void pass1_gl(const float* __restrict__ x, const float* __restrict__ cb,
              const unsigned short* __restrict__ cbh, const unsigned short* __restrict__ cbl,
              const float* __restrict__ cbsq, const float* __restrict__ cmax,
              float* __restrict__ out, int* __restrict__ bcnt, int* __restrict__ bwl,
              unsigned long long* __restrict__ pbest)
{
    __shared__ __align__(1024) char sm[73728];   // 64K tiles + 8K csq table
    const int tid  = threadIdx.x;
    const int lane = tid & 63, wv = tid >> 6;
    const int l15  = lane & 15, quad = lane >> 4;
    const int c = blockIdx.y, mbase = blockIdx.x * 128;
    const float4* xg = (const float4*)x;
    const float4* cg = (const float4*)cb;
    const float cmaxs = sqrtf(*cmax);
    const int cwb = (wv & 1) * 64, tkb = (wv >> 1) * 64;

    char* bufA = sm;            // x-stage hi @0, lo @16384; then odd tiles
    char* bufB = sm + 32768;    // tile 0 and even tiles (hi @0, lo @16384)
    float* csq_l = (float*)(sm + 65536);   // fp32 cbsq for this chunk (2048)

    // pre-swizzled per-lane global source offset: LDS off o = chunk + lane*16
    // -> row&7 = lane>>3, phys = lane&7 -> logical ch = (lane&7)^(lane>>3)
    const int lanebyte = ((lane >> 3) << 7) | ((((lane & 7) ^ (lane >> 3)) & 7) << 4);
    const char* srcH = (const char*)cbh + (size_t)c * NCODE * 128;  // 128 B/codeword
    const char* srcL = (const char*)cbl + (size_t)c * NCODE * 128;
    const int wchunk = wv * 4096;   // wave's 4KB slice of a 16KB half-tile

    // issue tile-0 DMA + csq-table DMA (linear) + x loads first
#pragma unroll
    for (int j = 0; j < 4; ++j) {
        const int o = wchunk + j * 1024;
        gload16(srcH + o + lanebyte, bufB + o);
        gload16(srcL + o + lanebyte, bufB + 16384 + o);
    }
    {
        const char* cq = (const char*)(cbsq + (size_t)c * NCODE);
#pragma unroll
        for (int j = 0; j < 2; ++j) {
            const int o = wv * 2048 + j * 1024;      // wave-uniform dest base
            gload16(cq + o + lane * 16, (char*)csq_l + o);
        }
    }
    float4 xf[8];
#pragma unroll
    for (int i = 0; i < 8; ++i) {
        const int flat = i * 256 + tid;
        xf[i] = xg[(size_t)(mbase + (flat >> 4)) * 256 + c * 16 + (flat & 15)];
    }

    // ---- reg-built calibration: decode MFMA D-layout slot -> (t_hat, n_hat)
    int tdec[4], ndec[4];
    {
        const short one = (short)bf16_rne(1.0f);
        const short val = (short)bf16_rne((float)l15);
        s16x8 aV, aO;
#pragma unroll
        for (int e = 0; e < 8; ++e) { aV[e] = val; aO[e] = one; }
        f32x4 z; z[0] = z[1] = z[2] = z[3] = 0.f;
        const f32x4 at = __builtin_amdgcn_mfma_f32_16x16x32_bf16(aO, aV, z, 0, 0, 0);
        const f32x4 an = __builtin_amdgcn_mfma_f32_16x16x32_bf16(aV, aO, z, 0, 0, 0);
#pragma unroll
        for (int r = 0; r < 4; ++r) {
            tdec[r] = ((int)(at[r] + 0.5f) >> 5) & 15;   // D-col (token)
            ndec[r] = ((int)(an[r] + 0.5f) >> 5) & 15;   // D-row (codeword)
        }
    }

    // ---- stage x (split bf16, swizzled) into bufA; |x|^2 partials in regs
    float p8[8];
#pragma unroll
    for (int i = 0; i < 8; ++i) {
        const int flat = i * 256 + tid, row = flat >> 4, f4c = flat & 15;
        ushort4 h, l; split4(xf[i], h, l);
        const int off = row * 128 + ((((f4c >> 1) ^ row) & 7) * 16) + (f4c & 1) * 8;
        *(ushort4*)(bufA + off) = h;
        *(ushort4*)(bufA + 16384 + off) = l;
        p8[i] = xf[i].x * xf[i].x + xf[i].y * xf[i].y + xf[i].z * xf[i].z + xf[i].w * xf[i].w;
    }
    __syncthreads();   // drains vmcnt -> tile0 + csq table resident; xs visible

    // hoist token (B) fragments for the whole nt loop
    s16x8 bhf[4][2], blf[4][2];
#pragma unroll
    for (int jt = 0; jt < 4; ++jt)
#pragma unroll
        for (int ks = 0; ks < 2; ++ks) {
            const int rowt = tkb + jt * 16 + l15;
            const int ke = ks * 32 + quad * 8;
            bhf[jt][ks] = ldfrag(bufA, rowt, ke);
            blf[jt][ks] = ldfrag(bufA + 16384, rowt, ke);
        }
    __syncthreads();   // all hoists done before nt=0 DMAs tile 1 into bufA

    float s1[4][4], s2[4][4]; int i1[4][4];
#pragma unroll
    for (int jt = 0; jt < 4; ++jt)
#pragma unroll
        for (int r = 0; r < 4; ++r) { s1[jt][r] = 3.4e38f; s2[jt][r] = 3.4e38f; i1[jt][r] = 0; }

    for (int nt = 0; nt < 16; ++nt) {
        char* chi = (nt & 1) ? bufA : bufB;
        char* clo = chi + 16384;

        if (nt < 15) {
            char* nh = (nt & 1) ? bufB : bufA;
            const char* th = srcH + (size_t)(nt + 1) * 16384;
            const char* tl = srcL + (size_t)(nt + 1) * 16384;
#pragma unroll
            for (int j = 0; j < 4; ++j) {
                const int o = wchunk + j * 1024;
                gload16(th + o + lanebyte, nh + o);
                gload16(tl + o + lanebyte, nh + 16384 + o);
            }
        }

        // csq from LDS (broadcast ds_read) -- no global loads in loop body
        float csqv[4][4];
#pragma unroll
        for (int mt = 0; mt < 4; ++mt)
#pragma unroll
            for (int r = 0; r < 4; ++r)
                csqv[mt][r] = csq_l[nt * 128 + cwb + mt * 16 + ndec[r]];

#pragma unroll
        for (int mt = 0; mt < 4; ++mt) {
            f32x4 accj[4];
#pragma unroll
            for (int jt = 0; jt < 4; ++jt)
#pragma unroll
                for (int e = 0; e < 4; ++e) accj[jt][e] = 0.f;
#pragma unroll
            for (int ks = 0; ks < 2; ++ks) {
                const int ke = ks * 32 + quad * 8;
                const int rowc = cwb + mt * 16 + l15;
                const s16x8 ah = ldfrag(chi, rowc, ke);
                const s16x8 al = ldfrag(clo, rowc, ke);
#pragma unroll
                for (int jt = 0; jt < 4; ++jt) {
                    accj[jt] = __builtin_amdgcn_mfma_f32_16x16x32_bf16(ah, bhf[jt][ks], accj[jt], 0, 0, 0);
                    accj[jt] = __builtin_amdgcn_mfma_f32_16x16x32_bf16(ah, blf[jt][ks], accj[jt], 0, 0, 0);
                    accj[jt] = __builtin_amdgcn_mfma_f32_16x16x32_bf16(al, bhf[jt][ks], accj[jt], 0, 0, 0);
                }
            }
            // n ascending in (nt,mt) per slot => strict < keeps first-index min
            // med3(s, s1, s2) == exact new second-best (s1<=s2 invariant)
#pragma unroll
            for (int jt = 0; jt < 4; ++jt)
#pragma unroll
                for (int r = 0; r < 4; ++r) {
                    const float s = fmaf(-2.f, accj[jt][r], csqv[mt][r]);
                    const int n = nt * 128 + cwb + mt * 16 + ndec[r];
                    const bool lt = s < s1[jt][r];
                    s2[jt][r] = med3f(s, s1[jt][r], s2[jt][r]);
                    i1[jt][r] = lt ? n : i1[jt][r];
                    s1[jt][r] = fminf(s1[jt][r], s);
                }
        }
        __syncthreads();   // drains vmcnt: tile nt+1 resident; cur readers done
    }

    // ---- epilogue: in-register r-merge + quad shuffle top-2 reduce ----
    float* s1h = (float*)sm;             // [128][2]
    int*   i1h = (int*)  (sm + 1024);    // [128][2]
    float* s2h = (float*)(sm + 2048);    // [128][2]
    float* xsq_l = (float*)(sm + 3072);  // [128]
    int*   bfin  = (int*)  (sm + 3584);  // [128]

#pragma unroll
    for (int jt = 0; jt < 4; ++jt) {
        float b1 = s1[jt][0], b2 = s2[jt][0]; int bi = i1[jt][0];
#pragma unroll
        for (int r = 1; r < 4; ++r)
            merge2(b1, bi, b2, s1[jt][r], i1[jt][r], s2[jt][r]);
        // reduce across the 4 quads (lanes l15, +16, +32, +48: same token)
#pragma unroll
        for (int m = 16; m <= 32; m <<= 1) {
            const float ob1 = __shfl_xor(b1, m);
            const int   obi = __shfl_xor(bi, m);
            const float ob2 = __shfl_xor(b2, m);
            merge2(b1, bi, b2, ob1, obi, ob2);
        }
        if (quad == 0) {
            const int tok = tkb + jt * 16 + tdec[0];
            s1h[tok * 2 + (wv & 1)] = b1;
            i1h[tok * 2 + (wv & 1)] = bi;
            s2h[tok * 2 + (wv & 1)] = b2;
        }
    }
    // xsq: 16 partials per token live in one 16-lane group
#pragma unroll
    for (int i = 0; i < 8; ++i) {
        float v = p8[i];
        v += __shfl_xor(v, 1); v += __shfl_xor(v, 2);
        v += __shfl_xor(v, 4); v += __shfl_xor(v, 8);
        if (l15 == 0) xsq_l[i * 16 + (tid >> 4)] = v;
    }
    __syncthreads();
    if (tid < 128) {
        float b1 = s1h[tid * 2], b2 = s2h[tid * 2]; int bi = i1h[tid * 2];
        merge2(b1, bi, b2, s1h[tid * 2 + 1], i1h[tid * 2 + 1], s2h[tid * 2 + 1]);
        const float xsq = xsq_l[tid];
        const float eps = 3e-4f + 2e-4f * sqrtf(xsq) * cmaxs;
        bfin[tid] = bi;
        if (b2 - b1 <= 2.f * eps) {
            const int slot = atomicAdd(&bcnt[c], 1);   // slot < 8192 structurally
            bwl[c * 8192 + slot] = mbase + tid;
            pbest[c * 8192 + slot] = ~0ULL;            // init merge cell
        }
    }
    __syncthreads();
    {
        float4* og = (float4*)out;
#pragma unroll
        for (int i = 0; i < 8; ++i) {
            const int flat = i * 256 + tid, m = flat >> 4, q = flat & 15;
            og[(size_t)(mbase + m) * 256 + c * 16 + q] =
                cg[((size_t)c * NCODE + bfin[m]) * 16 + q];
        }
    }
}

// ====== pass 2: exact fp32 rescore, PARALLEL over 16 codeword tiles ======
__global__ __launch_bounds__(256, 2)
void pass2_nt(const float* __restrict__ x, const float* __restrict__ cb,
              const int* __restrict__ bcnt, const int* __restrict__ bwl,
              unsigned long long* __restrict__ pbest)
{
    __shared__ __align__(16) char smraw[65536];
    __shared__ int toks[128];
    float4 (*xs)[128] = reinterpret_cast<float4(*)[128]>(smraw);
    float4 (*cs)[128] = reinterpret_cast<float4(*)[128]>(smraw + 32768);
    float  (*rs)[128] = reinterpret_cast<float(*)[128]>(smraw);
    int    (*ri)[128] = reinterpret_cast<int(*)[128]>(smraw + 8192);

    const int c = blockIdx.y, ntb = blockIdx.x;
    const int cnt = bcnt[c];
    if (cnt == 0) return;
    const int tid = threadIdx.x, tx = tid & 15, ty = tid >> 4;
    const float4* xg = (const float4*)x;
    const float4* cg = (const float4*)cb;

    {
        const int k4 = tid & 15, nrow0 = tid >> 4;
#pragma unroll
        for (int i = 0; i < 8; ++i) {
            const int n = i * 16 + nrow0;
            cs[k4][n] = cg[((size_t)c * NCODE + ntb * 128 + n) * 16 + k4];
        }
    }

    for (int g0 = 0; g0 < cnt; g0 += 128) {
        __syncthreads();
        if (tid < 128) {
            const int e = g0 + tid;
            toks[tid] = bwl[c * 8192 + (e < cnt ? e : g0)];
        }
        __syncthreads();
        {
            const int k4 = tid & 15, mrow0 = tid >> 4;
#pragma unroll
            for (int i = 0; i < 8; ++i) {
                const int m = i * 16 + mrow0;
                xs[k4][m] = xg[(size_t)toks[m] * 256 + c * 16 + k4];
            }
        }
        __syncthreads();
        float acc[8][8], csq[8];
#pragma unroll
        for (int ii = 0; ii < 8; ++ii)
#pragma unroll
            for (int jj = 0; jj < 8; ++jj) acc[ii][jj] = 0.f;
#pragma unroll
        for (int jj = 0; jj < 8; ++jj) csq[jj] = 0.f;
#pragma unroll 2
        for (int k4 = 0; k4 < 16; ++k4) {
            float4 xv[8], cv[8];
#pragma unroll
            for (int ii = 0; ii < 8; ++ii) xv[ii] = xs[k4][tx + 16 * ii];
#pragma unroll
            for (int jj = 0; jj < 8; ++jj) cv[jj] = cs[k4][ty + 16 * jj];
#pragma unroll
            for (int jj = 0; jj < 8; ++jj) {
                csq[jj] = fmaf(cv[jj].x, cv[jj].x, csq[jj]);
                csq[jj] = fmaf(cv[jj].y, cv[jj].y, csq[jj]);
                csq[jj] = fmaf(cv[jj].z, cv[jj].z, csq[jj]);
                csq[jj] = fmaf(cv[jj].w, cv[jj].w, csq[jj]);
            }
#pragma unroll
            for (int ii = 0; ii < 8; ++ii)
#pragma unroll
                for (int jj = 0; jj < 8; ++jj) {
                    acc[ii][jj] = fmaf(xv[ii].x, cv[jj].x, acc[ii][jj]);
                    acc[ii][jj] = fmaf(xv[ii].y, cv[jj].y, acc[ii][jj]);
                    acc[ii][jj] = fmaf(xv[ii].z, cv[jj].z, acc[ii][jj]);
                    acc[ii][jj] = fmaf(xv[ii].w, cv[jj].w, acc[ii][jj]);
                }
        }
        float best[8]; int bidx[8];
#pragma unroll
        for (int ii = 0; ii < 8; ++ii) { best[ii] = 3.4e38f; bidx[ii] = 0; }
#pragma unroll
        for (int jj = 0; jj < 8; ++jj) {
            const int n = ntb * 128 + ty + 16 * jj;
#pragma unroll
            for (int ii = 0; ii < 8; ++ii) {
                const float s = fmaf(-2.f, acc[ii][jj], csq[jj]);
                if (s < best[ii]) { best[ii] = s; bidx[ii] = n; }
            }
        }
        __syncthreads();
#pragma unroll
        for (int ii = 0; ii < 8; ++ii) {
            const int m = tx + 16 * ii;
            rs[ty][m] = best[ii]; ri[ty][m] = bidx[ii];
        }
        __syncthreads();
        if (tid < 128 && g0 + tid < cnt) {
            float b = rs[0][tid]; int bi = ri[0][tid];
#pragma unroll
            for (int j = 1; j < 16; ++j) {
                const float s = rs[j][tid]; const int i2 = ri[j][tid];
                if (s < b || (s == b && i2 < bi)) { b = s; bi = i2; }
            }
            const unsigned long long pk =
                ((unsigned long long)enc_f(b) << 32) | (unsigned)bi;
            atomicMin(&pbest[c * 8192 + g0 + tid], pk);
        }
    }
}

// ====== pass 3: gather winners for flagged tokens ======
__global__ void pass3(const float* __restrict__ cb, float* __restrict__ out,
                      const int* __restrict__ bcnt, const int* __restrict__ bwl,
                      const unsigned long long* __restrict__ pbest)
{
    const int c = blockIdx.y;
    const int cnt = bcnt[c];
    const float4* cg = (const float4*)cb;
    float4* og = (float4*)out;
    const int q = threadIdx.x & 15;
    for (int e = blockIdx.x * 16 + (threadIdx.x >> 4); e < cnt; e += 64 * 16) {
        const int tok = bwl[c * 8192 + e];
        const unsigned n = (unsigned)(pbest[c * 8192 + e] & 0xFFFFFFFFull);
        og[(size_t)tok * 256 + c * 16 + q] = cg[((size_t)c * NCODE + n) * 16 + q];
    }
}

extern "C" void kernel_launch(void* const* d_in, const int* in_sizes, int n_in,
                              void* d_out, int out_size, void* d_ws, size_t ws_size,
                              hipStream_t stream)
{
    const float* x  = (const float*)d_in[0];
    const float* cb = (const float*)d_in[1];
    float* out      = (float*)d_out;

    if (ws_size < (size_t)(2u << 20)) {
        dim3 grid(BS / 128, CCH);
        vq_fp32_fallback<<<grid, 256, 0, stream>>>(x, cb, out);
        return;
    }
    char* ws = (char*)d_ws;
    float* cbsq = (float*)ws;
    float* cmax = (float*)(ws + 131072);
    int*   bcnt = (int*)(ws + 131076);
    int*   bwl  = (int*)(ws + 131328);
    unsigned long long* pbest = (unsigned long long*)(ws + 655616);
    unsigned short* cbh = (unsigned short*)(ws + (2u << 20));
    unsigned short* cbl = (unsigned short*)(ws + (6u << 20));

    // cmax (4B) + bcnt[16] (64B) are contiguous: one capture-safe memset
    hipMemsetAsync(ws + 131072, 0, 68, stream);
    cbsq_kernel<<<CCH * NCODE / 256, 256, 0, stream>>>(cb, cbsq, cmax);
    if (ws_size >= (size_t)(10u << 20)) {
        presplit_cb<<<2048, 256, 0, stream>>>(cb, cbh, cbl);
        pass1_gl<<<dim3(BS / 128, CCH), 256, 0, stream>>>(x, cb, cbh, cbl, cbsq, cmax, out, bcnt, bwl, pbest);
    } else {
        pass1<false><<<dim3(BS / 128, CCH), 256, 0, stream>>>(x, cb, nullptr, nullptr, cbsq, cmax, out, bcnt, bwl, pbest);
    }
    pass2_nt<<<dim3(16, CCH), 256, 0, stream>>>(x, cb, bcnt, bwl, pbest);
    pass3<<<dim3(64, CCH), 256, 0, stream>>>(cb, out, bcnt, bwl, pbest);
}